// Round 1
// baseline (201.162 us; speedup 1.0000x reference)
//
#include <hip/hip_runtime.h>

#define B_  8
#define QL_ 128
#define ML_ 1024
#define KS_ 512
#define H_  256

// ws layout (floats):
//   Eq = exp2(2log2e * qproj): [B][QL][H]  @ 0        (262144 floats)
//   Ek = exp2(2log2e * kproj): [B][ML][H]  @ 262144   (2097152 floats)
//   mask canonical uint8 [B*ML]            @ 2359296  (8192 bytes)
#define QP_OFF 0
#define KP_OFF 262144
#define MASK_OFF 2359296

// ---------------------------------------------------------------------------
// Fused projection kernel: flat grid of 1153 blocks.
//   bid 0..127    : q-proj  (bm = bid>>2, bn = bid&3), M=1024
//   bid 128..1151 : k-proj  (bm = (bid-128)>>2, bn = &3), M=8192
//   bid 1152      : mask canonicalizer
// GEMM: out[m][n] = exp2( SC * (sum_k X[m][k]*W[n][k] + bias[n]) ), K=512, N=256.
// 32x64 tile, TK=32, 2x4 microtile, ping-pong LDS (1 barrier/chunk),
// register prefetch. 1152 blocks = 4.5 blocks/CU = 4.5 waves/SIMD — the
// previous 64x64/577-block version sat at 2.25 waves/SIMD (Occupancy 15.8%,
// VALUBusy 40%): latency-bound, not BW-bound. Accumulation order per output
// is unchanged (k = 0..511 sequential) so results are bit-identical.
// ---------------------------------------------------------------------------
__global__ __launch_bounds__(256) void proj_kernel(
    const float* __restrict__ query, const float* __restrict__ memory,
    const float* __restrict__ Wq, const float* __restrict__ bq,
    const float* __restrict__ Wk, const float* __restrict__ bk,
    float* __restrict__ Eq, float* __restrict__ Ek,
    const unsigned char* __restrict__ mraw, unsigned char* __restrict__ mout) {
    const int bid = blockIdx.x;
    const int t = threadIdx.x;

    if (bid == 1152) {   // ---- mask canonicalizer ----
        __shared__ int s_not01, s_not0f;
        const unsigned int* w = (const unsigned int*)mraw;
        if (t == 0) { s_not01 = 0; s_not0f = 0; }
        __syncthreads();
        int not01 = 0, not0f = 0;
        for (int i = t; i < 2048; i += 256) {
            unsigned int v = w[i];
            if (v != 0u && v != 1u) not01 = 1;
            if (v != 0u && v != 0x3F800000u) not0f = 1;
        }
        if (not01) atomicOr(&s_not01, 1);
        if (not0f) atomicOr(&s_not0f, 1);
        __syncthreads();
        int wordTyped = (!s_not01) || (!s_not0f);
        for (int i = t; i < B_ * ML_; i += 256) {
            unsigned char mv;
            if (wordTyped) mv = (w[i] != 0u) ? 1 : 0;
            else           mv = mraw[i] ? 1 : 0;
            mout[i] = mv;
        }
        return;
    }

    const float SC = 2.885390081777926815f;   // 2*log2(e)
    const int K = 512, N = 256;
    __shared__ float Xs[2][32][34];
    __shared__ float Ws[2][32][68];

    const float *X, *W, *bias; float* out; int bm, bn;
    if (bid < 128) { X = query;  W = Wq; bias = bq; out = Eq; bm = bid >> 2;         bn = bid & 3; }
    else           { X = memory; W = Wk; bias = bk; out = Ek; bm = (bid - 128) >> 2; bn = (bid - 128) & 3; }

    // staging map: each thread loads one float4 of A (32x32 chunk) and two
    // float4 of B (64x32 chunk) per TK=32 chunk.
    const int ar = t >> 3;            // 0..31
    const int ak = (t & 7) << 2;      // 0,4,..,28
    const float* Xrow  = X + (size_t)(bm * 32 + ar) * K + ak;
    const float* Wrow0 = W + (size_t)(bn * 64 + ar) * K + ak;
    const float* Wrow1 = W + (size_t)(bn * 64 + ar + 32) * K + ak;

    const int tx = t & 15, ty = t >> 4;   // micro: rows ty*2+{0,1}, cols tx*4+{0..3}
    float acc[2][4] = {};

    // prologue: chunk 0 -> buf 0, prefetch chunk 1 into regs
    float4 xa  = *(const float4*)(Xrow);
    float4 wa0 = *(const float4*)(Wrow0);
    float4 wa1 = *(const float4*)(Wrow1);
    Xs[0][ak + 0][ar] = xa.x;  Xs[0][ak + 1][ar] = xa.y;
    Xs[0][ak + 2][ar] = xa.z;  Xs[0][ak + 3][ar] = xa.w;
    Ws[0][ak + 0][ar] = wa0.x; Ws[0][ak + 1][ar] = wa0.y;
    Ws[0][ak + 2][ar] = wa0.z; Ws[0][ak + 3][ar] = wa0.w;
    Ws[0][ak + 0][ar + 32] = wa1.x; Ws[0][ak + 1][ar + 32] = wa1.y;
    Ws[0][ak + 2][ar + 32] = wa1.z; Ws[0][ak + 3][ar + 32] = wa1.w;
    xa  = *(const float4*)(Xrow + 32);
    wa0 = *(const float4*)(Wrow0 + 32);
    wa1 = *(const float4*)(Wrow1 + 32);
    __syncthreads();

    for (int c = 0; c < 16; ++c) {
        const int p = c & 1;
        if (c < 15) {
            // write prefetched chunk c+1 into the other buffer (safe: the
            // barrier at end of iter c-1 guarantees everyone is done reading it)
            Xs[p ^ 1][ak + 0][ar] = xa.x;  Xs[p ^ 1][ak + 1][ar] = xa.y;
            Xs[p ^ 1][ak + 2][ar] = xa.z;  Xs[p ^ 1][ak + 3][ar] = xa.w;
            Ws[p ^ 1][ak + 0][ar] = wa0.x; Ws[p ^ 1][ak + 1][ar] = wa0.y;
            Ws[p ^ 1][ak + 2][ar] = wa0.z; Ws[p ^ 1][ak + 3][ar] = wa0.w;
            Ws[p ^ 1][ak + 0][ar + 32] = wa1.x; Ws[p ^ 1][ak + 1][ar + 32] = wa1.y;
            Ws[p ^ 1][ak + 2][ar + 32] = wa1.z; Ws[p ^ 1][ak + 3][ar + 32] = wa1.w;
            if (c < 14) {
                xa  = *(const float4*)(Xrow  + (c + 2) * 32);
                wa0 = *(const float4*)(Wrow0 + (c + 2) * 32);
                wa1 = *(const float4*)(Wrow1 + (c + 2) * 32);
            }
        }
#pragma unroll
        for (int k = 0; k < 32; ++k) {
            float2 a2 = *(const float2*)(&Xs[p][k][ty * 2]);
            float4 b4 = *(const float4*)(&Ws[p][k][tx * 4]);
            acc[0][0] = fmaf(a2.x, b4.x, acc[0][0]);
            acc[0][1] = fmaf(a2.x, b4.y, acc[0][1]);
            acc[0][2] = fmaf(a2.x, b4.z, acc[0][2]);
            acc[0][3] = fmaf(a2.x, b4.w, acc[0][3]);
            acc[1][0] = fmaf(a2.y, b4.x, acc[1][0]);
            acc[1][1] = fmaf(a2.y, b4.y, acc[1][1]);
            acc[1][2] = fmaf(a2.y, b4.z, acc[1][2]);
            acc[1][3] = fmaf(a2.y, b4.w, acc[1][3]);
        }
        __syncthreads();
    }

    float4 bv = *(const float4*)(bias + bn * 64 + tx * 4);
    float bvec[4] = {bv.x, bv.y, bv.z, bv.w};
#pragma unroll
    for (int i = 0; i < 2; ++i) {
        int m = bm * 32 + ty * 2 + i;
        float4 o;
        o.x = __builtin_amdgcn_exp2f(SC * (acc[i][0] + bvec[0]));
        o.y = __builtin_amdgcn_exp2f(SC * (acc[i][1] + bvec[1]));
        o.z = __builtin_amdgcn_exp2f(SC * (acc[i][2] + bvec[2]));
        o.w = __builtin_amdgcn_exp2f(SC * (acc[i][3] + bvec[3]));
        *(float4*)(out + (size_t)m * N + bn * 64 + tx * 4) = o;
    }
}

// ---------------------------------------------------------------------------
// sr[b][q][m] = sum_h wl[h] / (Eq[b][q][h]*Ek[b][m][h] + 1)
// (tanh folded: tanh(v) = 1 - 2/(e^{2v}+1); exp precomputed -> p = fma(Ek,Eq,1))
// 4-way reciprocal grouping: sum w_i/p_i = N/(p0 p1 p2 p3) -> 1 rcp per 4 h.
// Block: 256 threads; m-tile 128 (lane m = tid&127), q-octet split in halves
// (qh = tid>>7 -> 4 q's per thread). Eq tile + wl staged ONCE in LDS;
// Ek chunked 16-h with quad-blocked layout for aligned ds_read_b128.
// Grid 1024 blocks (4/CU); b = bid&7 for XCD L2 affinity on Ek.
// ---------------------------------------------------------------------------
__global__ __launch_bounds__(256) void logits_kernel(
    const float* __restrict__ Eq, const float* __restrict__ Ek,
    const float* __restrict__ wl, float* __restrict__ sr) {
    const int bid = blockIdx.x;
    const int b  = bid & 7;
    const int r2 = bid >> 3;
    const int mt = r2 & 7;      // m tile of 128
    const int qt = r2 >> 3;     // q octet
    const int tid = threadIdx.x;
    const int m  = tid & 127;
    const int qh = tid >> 7;    // 0/1: which 4 q's

    __shared__ float eqs[2048];        // [j][h], j<8
    __shared__ float wls[256];
    __shared__ float kq[4][128][4];    // [h-quad][m][4], 16B-aligned slots

    const float* qpb = Eq + ((size_t)(b * QL_ + qt * 8)) * H_;
    const float* kpb = Ek + ((size_t)(b * ML_ + mt * 128)) * H_;

    // one-time stage: Eq tile (2048 contiguous floats) + wl (256 floats)
    *(float4*)(&eqs[tid * 4])        = *(const float4*)(qpb + tid * 4);
    *(float4*)(&eqs[1024 + tid * 4]) = *(const float4*)(qpb + 1024 + tid * 4);
    if (tid < 64) *(float4*)(&wls[tid * 4]) = *(const float4*)(wl + tid * 4);

    // Ek staging map: lane covers row srow, h-range [8*sq2, 8*sq2+8) of chunk
    const int srow = tid & 127;
    const int sq2  = tid >> 7;
    const float* kst = kpb + (size_t)srow * H_ + 8 * sq2;
    float4 a0 = *(const float4*)(kst);
    float4 a1 = *(const float4*)(kst + 4);

    float acc[4] = {0.f, 0.f, 0.f, 0.f};

    for (int c = 0; c < 16; ++c) {
        __syncthreads();
        *(float4*)(&kq[2 * sq2 + 0][srow][0]) = a0;
        *(float4*)(&kq[2 * sq2 + 1][srow][0]) = a1;
        __syncthreads();
        if (c < 15) {
            a0 = *(const float4*)(kst + (c + 1) * 16);
            a1 = *(const float4*)(kst + (c + 1) * 16 + 4);
        }
        const int h0 = c * 16;
#pragma unroll
        for (int quad = 0; quad < 4; ++quad) {
            float4 k4 = *(const float4*)(&kq[quad][m][0]);
            float4 w4 = *(const float4*)(&wls[h0 + quad * 4]);
#pragma unroll
            for (int j2 = 0; j2 < 4; ++j2) {
                float4 q4 = *(const float4*)(&eqs[(qh * 4 + j2) * 256 + h0 + quad * 4]);
                float p0 = fmaf(k4.x, q4.x, 1.0f);
                float p1 = fmaf(k4.y, q4.y, 1.0f);
                float p2 = fmaf(k4.z, q4.z, 1.0f);
                float p3 = fmaf(k4.w, q4.w, 1.0f);
                float p01 = p0 * p1, p23 = p2 * p3;
                float n01 = fmaf(w4.y, p0, w4.x * p1);
                float n23 = fmaf(w4.w, p2, w4.z * p3);
                float Nm  = fmaf(n23, p01, n01 * p23);
                float P   = p01 * p23;
                acc[j2] = fmaf(Nm, __builtin_amdgcn_rcpf(P), acc[j2]);
            }
        }
    }
#pragma unroll
    for (int j2 = 0; j2 < 4; ++j2)
        sr[((size_t)(b * QL_ + qt * 8 + qh * 4 + j2)) * ML_ + mt * 128 + m] = acc[j2];
}

// ---------------------------------------------------------------------------
// In-place masked softmax (unchanged). logits_eff = -2*sr (shift-invariant).
// ---------------------------------------------------------------------------
__global__ __launch_bounds__(256) void softmax_kernel(
    float* __restrict__ wrow_io, const unsigned char* __restrict__ mv) {
    const int row = blockIdx.x;
    const int b = row >> 7;
    const int tid = threadIdx.x;
    float* srow = wrow_io + (size_t)row * ML_;
    const unsigned char* mrow = mv + b * ML_;
    __shared__ float red[4];

    float4 s4 = *(const float4*)(srow + tid * 4);
    uchar4 m4 = *(const uchar4*)(mrow + tid * 4);
    float l[4];
    l[0] = m4.x ? -1e18f : -2.0f * s4.x;
    l[1] = m4.y ? -1e18f : -2.0f * s4.y;
    l[2] = m4.z ? -1e18f : -2.0f * s4.z;
    l[3] = m4.w ? -1e18f : -2.0f * s4.w;

    float mx = fmaxf(fmaxf(l[0], l[1]), fmaxf(l[2], l[3]));
#pragma unroll
    for (int off = 32; off >= 1; off >>= 1)
        mx = fmaxf(mx, __shfl_xor(mx, off));
    if ((tid & 63) == 0) red[tid >> 6] = mx;
    __syncthreads();
    mx = fmaxf(fmaxf(red[0], red[1]), fmaxf(red[2], red[3]));
    __syncthreads();

    const float L2E = 1.44269504088896340736f;
    float e[4], s = 0.f;
#pragma unroll
    for (int i = 0; i < 4; ++i) {
        e[i] = __builtin_amdgcn_exp2f((l[i] - mx) * L2E);
        s += e[i];
    }
#pragma unroll
    for (int off = 32; off >= 1; off >>= 1)
        s += __shfl_xor(s, off);
    if ((tid & 63) == 0) red[tid >> 6] = s;
    __syncthreads();
    s = (red[0] + red[1]) + (red[2] + red[3]);
    float inv = __builtin_amdgcn_rcpf(s);
    float4 o = make_float4(e[0] * inv, e[1] * inv, e[2] * inv, e[3] * inv);
    *(float4*)(srow + tid * 4) = o;
}

// ---------------------------------------------------------------------------
// attns[b] = W[b] (128x1024) @ M[b] (1024x512). LDS-tiled GEMM (unchanged).
// ---------------------------------------------------------------------------
__global__ __launch_bounds__(256) void attn_out_kernel(
    const float* __restrict__ wgt, const float* __restrict__ mem,
    float* __restrict__ out) {
    const int bid = blockIdx.x;
    const int b  = bid & 7;
    const int j2 = bid >> 3;
    const int mt = j2 & 3;
    const int nt = j2 >> 2;
    const int t = threadIdx.x;
    __shared__ float As[32][34];
    __shared__ float Bs[32][64];

    const int ar = t >> 3, ac = (t & 7) << 2;
    const int br = t >> 4, bc = (t & 15) << 2;
    const float* Ap = wgt + ((size_t)(b * QL_ + mt * 32 + ar)) * ML_ + ac;
    const float* Bp = mem + ((size_t)(b * ML_ + br)) * KS_ + nt * 64 + bc;

    const int tx = t & 15, ty = t >> 4;
    float acc0[4] = {0.f, 0.f, 0.f, 0.f};
    float acc1[4] = {0.f, 0.f, 0.f, 0.f};

    float4 apre = *(const float4*)(Ap);
    float4 bpre0 = *(const float4*)(Bp);
    float4 bpre1 = *(const float4*)(Bp + (size_t)16 * KS_);

    for (int k0 = 0; k0 < ML_; k0 += 32) {
        __syncthreads();
        As[ac + 0][ar] = apre.x; As[ac + 1][ar] = apre.y;
        As[ac + 2][ar] = apre.z; As[ac + 3][ar] = apre.w;
        *(float4*)(&Bs[br][bc])      = bpre0;
        *(float4*)(&Bs[br + 16][bc]) = bpre1;
        __syncthreads();
        if (k0 + 32 < ML_) {
            apre  = *(const float4*)(Ap + k0 + 32);
            bpre0 = *(const float4*)(Bp + (size_t)(k0 + 32) * KS_);
            bpre1 = *(const float4*)(Bp + (size_t)(k0 + 48) * KS_);
        }
#pragma unroll
        for (int kk = 0; kk < 32; ++kk) {
            float2 a2 = *(const float2*)(&As[kk][ty * 2]);
            float4 b4 = *(const float4*)(&Bs[kk][tx * 4]);
            acc0[0] = fmaf(a2.x, b4.x, acc0[0]);
            acc0[1] = fmaf(a2.x, b4.y, acc0[1]);
            acc0[2] = fmaf(a2.x, b4.z, acc0[2]);
            acc0[3] = fmaf(a2.x, b4.w, acc0[3]);
            acc1[0] = fmaf(a2.y, b4.x, acc1[0]);
            acc1[1] = fmaf(a2.y, b4.y, acc1[1]);
            acc1[2] = fmaf(a2.y, b4.z, acc1[2]);
            acc1[3] = fmaf(a2.y, b4.w, acc1[3]);
        }
    }
    size_t orow = ((size_t)(b * QL_ + mt * 32 + ty * 2)) * KS_ + nt * 64 + tx * 4;
    *(float4*)(out + orow)       = make_float4(acc0[0], acc0[1], acc0[2], acc0[3]);
    *(float4*)(out + orow + KS_) = make_float4(acc1[0], acc1[1], acc1[2], acc1[3]);
}

extern "C" void kernel_launch(void* const* d_in, const int* in_sizes, int n_in,
                              void* d_out, int out_size, void* d_ws, size_t ws_size,
                              hipStream_t stream) {
    const float* query  = (const float*)d_in[0];
    const float* memory = (const float*)d_in[1];
    const unsigned char* mask = (const unsigned char*)d_in[2];
    const float* Wq = (const float*)d_in[3];
    const float* bq = (const float*)d_in[4];
    const float* Wk = (const float*)d_in[5];
    const float* bk = (const float*)d_in[6];
    const float* wl = (const float*)d_in[7];
    // d_in[8] (bl) cancels under softmax shift-invariance; not read.

    float* ws = (float*)d_ws;
    float* Eq = ws + QP_OFF;
    float* Ek = ws + KP_OFF;
    unsigned char* mcan = (unsigned char*)(ws + MASK_OFF);

    float* attns = (float*)d_out;                      // [B][QL][KS]
    float* wout  = (float*)d_out + B_ * QL_ * KS_;     // [B][QL][ML] (also sr scratch)

    proj_kernel<<<dim3(1153), dim3(256), 0, stream>>>(query, memory, Wq, bq, Wk, bk,
                                                      Eq, Ek, mask, mcan);
    logits_kernel<<<dim3(1024), dim3(256), 0, stream>>>(Eq, Ek, wl, wout);
    softmax_kernel<<<dim3(B_ * QL_), dim3(256), 0, stream>>>(wout, mcan);
    attn_out_kernel<<<dim3(256), dim3(256), 0, stream>>>(wout, memory, attns);
}

// Round 2
// 180.093 us; speedup vs baseline: 1.1170x; 1.1170x over previous
//
#include <hip/hip_runtime.h>

#define B_  8
#define QL_ 128
#define ML_ 1024
#define KS_ 512
#define H_  256

// ws layout (floats):
//   Eq = exp2(2log2e * qproj): [B][QL][H]  @ 0        (262144 floats)
//   Ek = exp2(2log2e * kproj): [B][ML][H]  @ 262144   (2097152 floats)
//   mask canonical uint8 [B*ML]            @ 2359296  (8192 bytes)
#define QP_OFF 0
#define KP_OFF 262144
#define MASK_OFF 2359296

typedef __attribute__((ext_vector_type(8))) short bfrag;   // 8 bf16 (4 VGPR)
typedef __attribute__((ext_vector_type(4))) float f4acc;   // MFMA acc

// fp32 -> (hi,lo) bf16 split. hi = truncation (residual <= 2^-8|x|, captured
// exactly by fp32 subtract); lo = RNE of residual (final err <= 2^-17|x|).
// Dropped lo*lo cross term <= 2^-16 rel -> ~1e-5 abs in qproj. Negligible.
__device__ __forceinline__ void split8(const float4& a, const float4& b,
                                       bfrag& hi, bfrag& lo) {
    const float v[8] = {a.x, a.y, a.z, a.w, b.x, b.y, b.z, b.w};
#pragma unroll
    for (int j = 0; j < 8; ++j) {
        unsigned u  = __float_as_uint(v[j]);
        unsigned hb = u & 0xFFFF0000u;
        float    lf = v[j] - __uint_as_float(hb);     // exact
        unsigned ul = __float_as_uint(lf);
        unsigned lr = ul + 0x7FFFu + ((ul >> 16) & 1u);  // RNE
        hi[j] = (short)(u >> 16);
        lo[j] = (short)(lr >> 16);
    }
}

// ---------------------------------------------------------------------------
// Projection via bf16x3-split MFMA, NO LDS / NO barriers.
// Grid 145 blocks x 256 thr:
//   bid 0..15   : q-proj rows bid*64..+63      (M=1024)
//   bid 16..143 : k-proj rows (bid-16)*64..+63 (M=8192)
//   bid 144     : mask canonicalizer
// Block covers 64 m-rows x all 256 n (wave w owns n in [w*64, w*64+64)).
// mfma_f32_16x16x32_bf16 frag layout: A lane l -> row (l&15), k = 8*(l>>4)+j
// (contiguous); B lane l -> col (l&15), same k window. Both operands are
// K-contiguous row-major in memory -> each lane global-loads its OWN frag
// source directly (2 x float4 per tile per chunk). C/D: col=l&15,
// row=(l>>4)*4+reg  [m89-verified].
// Rationale: fp32-vector path was LDS-BW-bound (2-3 B/FMA vs 128 B/cyc/CU
// ceiling -> VALUBusy capped ~40-50%). MFMA-from-registers removes LDS
// entirely; X fetched once per block (4 waves share via L1), W stays L2-hot.
// ---------------------------------------------------------------------------
__global__ __launch_bounds__(256, 1) void proj_kernel(
    const float* __restrict__ query, const float* __restrict__ memory,
    const float* __restrict__ Wq, const float* __restrict__ bq,
    const float* __restrict__ Wk, const float* __restrict__ bk,
    float* __restrict__ Eq, float* __restrict__ Ek,
    const unsigned char* __restrict__ mraw, unsigned char* __restrict__ mout) {
    const int bid = blockIdx.x;
    const int t = threadIdx.x;

    if (bid == 144) {   // ---- mask canonicalizer ----
        __shared__ int s_not01, s_not0f;
        const unsigned int* w = (const unsigned int*)mraw;
        if (t == 0) { s_not01 = 0; s_not0f = 0; }
        __syncthreads();
        int not01 = 0, not0f = 0;
        for (int i = t; i < 2048; i += 256) {
            unsigned int v = w[i];
            if (v != 0u && v != 1u) not01 = 1;
            if (v != 0u && v != 0x3F800000u) not0f = 1;
        }
        if (not01) atomicOr(&s_not01, 1);
        if (not0f) atomicOr(&s_not0f, 1);
        __syncthreads();
        int wordTyped = (!s_not01) || (!s_not0f);
        for (int i = t; i < B_ * ML_; i += 256) {
            unsigned char mv;
            if (wordTyped) mv = (w[i] != 0u) ? 1 : 0;
            else           mv = mraw[i] ? 1 : 0;
            mout[i] = mv;
        }
        return;
    }

    const float SC = 2.885390081777926815f;   // 2*log2(e)
    const int K = 512, N = 256;

    const float *X, *W, *bias; float* out; int bm;
    if (bid < 16) { X = query;  W = Wq; bias = bq; out = Eq; bm = bid; }
    else          { X = memory; W = Wk; bias = bk; out = Ek; bm = bid - 16; }

    const int w  = t >> 6;    // wave id -> n group
    const int l  = t & 63;
    const int lr = l & 15;    // frag row/col within 16-tile
    const int lk = l >> 4;    // k-group -> k offset 8*lk within 32-chunk

    const float* Arow[4];
    const float* Brow[4];
#pragma unroll
    for (int i = 0; i < 4; ++i) {
        Arow[i] = X + (size_t)(bm * 64 + i * 16 + lr) * K + lk * 8;
        Brow[i] = W + (size_t)(w * 64 + i * 16 + lr) * K + lk * 8;
    }

    f4acc acc[4][4];
#pragma unroll
    for (int mi = 0; mi < 4; ++mi)
#pragma unroll
        for (int ni = 0; ni < 4; ++ni)
            acc[mi][ni] = (f4acc){0.f, 0.f, 0.f, 0.f};

    // double-buffered register prefetch (static buffer names: rule-#20 safe)
    float4 p0a[4][2], p0b[4][2], p1a[4][2], p1b[4][2];

#define LOADC(Pa, Pb, c) do {                                        \
    _Pragma("unroll")                                                \
    for (int i = 0; i < 4; ++i) {                                    \
        Pa[i][0] = *(const float4*)(Arow[i] + (c) * 32);             \
        Pa[i][1] = *(const float4*)(Arow[i] + (c) * 32 + 4);         \
        Pb[i][0] = *(const float4*)(Brow[i] + (c) * 32);             \
        Pb[i][1] = *(const float4*)(Brow[i] + (c) * 32 + 4);         \
    } } while (0)

#define COMPUTE(Pa, Pb) do {                                                   \
    bfrag ahi[4], alo[4], bhi[4], blo[4];                                      \
    _Pragma("unroll")                                                          \
    for (int i = 0; i < 4; ++i) split8(Pa[i][0], Pa[i][1], ahi[i], alo[i]);    \
    _Pragma("unroll")                                                          \
    for (int i = 0; i < 4; ++i) split8(Pb[i][0], Pb[i][1], bhi[i], blo[i]);    \
    _Pragma("unroll")                                                          \
    for (int mi = 0; mi < 4; ++mi)                                             \
    _Pragma("unroll")                                                          \
    for (int ni = 0; ni < 4; ++ni) {                                           \
        acc[mi][ni] = __builtin_amdgcn_mfma_f32_16x16x32_bf16(                 \
            ahi[mi], bhi[ni], acc[mi][ni], 0, 0, 0);                           \
        acc[mi][ni] = __builtin_amdgcn_mfma_f32_16x16x32_bf16(                 \
            ahi[mi], blo[ni], acc[mi][ni], 0, 0, 0);                           \
        acc[mi][ni] = __builtin_amdgcn_mfma_f32_16x16x32_bf16(                 \
            alo[mi], bhi[ni], acc[mi][ni], 0, 0, 0);                           \
    } } while (0)

    LOADC(p0a, p0b, 0);
    for (int c2 = 0; c2 < 8; ++c2) {
        LOADC(p1a, p1b, 2 * c2 + 1);      // issue next-chunk loads first
        COMPUTE(p0a, p0b);                // conversion+MFMA hides latency
        if (c2 < 7) LOADC(p0a, p0b, 2 * c2 + 2);
        COMPUTE(p1a, p1b);
    }
#undef LOADC
#undef COMPUTE

    // epilogue: bias + exp2, scattered-but-64B-coalesced dword stores
    float bcol[4];
#pragma unroll
    for (int ni = 0; ni < 4; ++ni) bcol[ni] = bias[w * 64 + ni * 16 + lr];

#pragma unroll
    for (int mi = 0; mi < 4; ++mi)
#pragma unroll
        for (int ni = 0; ni < 4; ++ni) {
            const int col = w * 64 + ni * 16 + lr;
#pragma unroll
            for (int r = 0; r < 4; ++r) {
                const int row = bm * 64 + mi * 16 + lk * 4 + r;
                out[(size_t)row * N + col] =
                    __builtin_amdgcn_exp2f(SC * (acc[mi][ni][r] + bcol[ni]));
            }
        }
}

// ---------------------------------------------------------------------------
// sr[b][q][m] = sum_h wl[h] / (Eq[b][q][h]*Ek[b][m][h] + 1)
// (tanh folded: tanh(v) = 1 - 2/(e^{2v}+1); exp precomputed -> p = fma(Ek,Eq,1))
// 4-way reciprocal grouping: sum w_i/p_i = N/(p0 p1 p2 p3) -> 1 rcp per 4 h.
// Block: 256 threads; m-tile 128 (lane m = tid&127), q-octet split in halves
// (qh = tid>>7 -> 4 q's per thread). Eq tile + wl staged ONCE in LDS;
// Ek chunked 16-h with quad-blocked layout for aligned ds_read_b128.
// Grid 1024 blocks (4/CU); b = bid&7 for XCD L2 affinity on Ek.
// ---------------------------------------------------------------------------
__global__ __launch_bounds__(256) void logits_kernel(
    const float* __restrict__ Eq, const float* __restrict__ Ek,
    const float* __restrict__ wl, float* __restrict__ sr) {
    const int bid = blockIdx.x;
    const int b  = bid & 7;
    const int r2 = bid >> 3;
    const int mt = r2 & 7;      // m tile of 128
    const int qt = r2 >> 3;     // q octet
    const int tid = threadIdx.x;
    const int m  = tid & 127;
    const int qh = tid >> 7;    // 0/1: which 4 q's

    __shared__ float eqs[2048];        // [j][h], j<8
    __shared__ float wls[256];
    __shared__ float kq[4][128][4];    // [h-quad][m][4], 16B-aligned slots

    const float* qpb = Eq + ((size_t)(b * QL_ + qt * 8)) * H_;
    const float* kpb = Ek + ((size_t)(b * ML_ + mt * 128)) * H_;

    // one-time stage: Eq tile (2048 contiguous floats) + wl (256 floats)
    *(float4*)(&eqs[tid * 4])        = *(const float4*)(qpb + tid * 4);
    *(float4*)(&eqs[1024 + tid * 4]) = *(const float4*)(qpb + 1024 + tid * 4);
    if (tid < 64) *(float4*)(&wls[tid * 4]) = *(const float4*)(wl + tid * 4);

    // Ek staging map: lane covers row srow, h-range [8*sq2, 8*sq2+8) of chunk
    const int srow = tid & 127;
    const int sq2  = tid >> 7;
    const float* kst = kpb + (size_t)srow * H_ + 8 * sq2;
    float4 a0 = *(const float4*)(kst);
    float4 a1 = *(const float4*)(kst + 4);

    float acc[4] = {0.f, 0.f, 0.f, 0.f};

    for (int c = 0; c < 16; ++c) {
        __syncthreads();
        *(float4*)(&kq[2 * sq2 + 0][srow][0]) = a0;
        *(float4*)(&kq[2 * sq2 + 1][srow][0]) = a1;
        __syncthreads();
        if (c < 15) {
            a0 = *(const float4*)(kst + (c + 1) * 16);
            a1 = *(const float4*)(kst + (c + 1) * 16 + 4);
        }
        const int h0 = c * 16;
#pragma unroll
        for (int quad = 0; quad < 4; ++quad) {
            float4 k4 = *(const float4*)(&kq[quad][m][0]);
            float4 w4 = *(const float4*)(&wls[h0 + quad * 4]);
#pragma unroll
            for (int j2 = 0; j2 < 4; ++j2) {
                float4 q4 = *(const float4*)(&eqs[(qh * 4 + j2) * 256 + h0 + quad * 4]);
                float p0 = fmaf(k4.x, q4.x, 1.0f);
                float p1 = fmaf(k4.y, q4.y, 1.0f);
                float p2 = fmaf(k4.z, q4.z, 1.0f);
                float p3 = fmaf(k4.w, q4.w, 1.0f);
                float p01 = p0 * p1, p23 = p2 * p3;
                float n01 = fmaf(w4.y, p0, w4.x * p1);
                float n23 = fmaf(w4.w, p2, w4.z * p3);
                float Nm  = fmaf(n23, p01, n01 * p23);
                float P   = p01 * p23;
                acc[j2] = fmaf(Nm, __builtin_amdgcn_rcpf(P), acc[j2]);
            }
        }
    }
#pragma unroll
    for (int j2 = 0; j2 < 4; ++j2)
        sr[((size_t)(b * QL_ + qt * 8 + qh * 4 + j2)) * ML_ + mt * 128 + m] = acc[j2];
}

// ---------------------------------------------------------------------------
// In-place masked softmax (unchanged). logits_eff = -2*sr (shift-invariant).
// ---------------------------------------------------------------------------
__global__ __launch_bounds__(256) void softmax_kernel(
    float* __restrict__ wrow_io, const unsigned char* __restrict__ mv) {
    const int row = blockIdx.x;
    const int b = row >> 7;
    const int tid = threadIdx.x;
    float* srow = wrow_io + (size_t)row * ML_;
    const unsigned char* mrow = mv + b * ML_;
    __shared__ float red[4];

    float4 s4 = *(const float4*)(srow + tid * 4);
    uchar4 m4 = *(const uchar4*)(mrow + tid * 4);
    float l[4];
    l[0] = m4.x ? -1e18f : -2.0f * s4.x;
    l[1] = m4.y ? -1e18f : -2.0f * s4.y;
    l[2] = m4.z ? -1e18f : -2.0f * s4.z;
    l[3] = m4.w ? -1e18f : -2.0f * s4.w;

    float mx = fmaxf(fmaxf(l[0], l[1]), fmaxf(l[2], l[3]));
#pragma unroll
    for (int off = 32; off >= 1; off >>= 1)
        mx = fmaxf(mx, __shfl_xor(mx, off));
    if ((tid & 63) == 0) red[tid >> 6] = mx;
    __syncthreads();
    mx = fmaxf(fmaxf(red[0], red[1]), fmaxf(red[2], red[3]));
    __syncthreads();

    const float L2E = 1.44269504088896340736f;
    float e[4], s = 0.f;
#pragma unroll
    for (int i = 0; i < 4; ++i) {
        e[i] = __builtin_amdgcn_exp2f((l[i] - mx) * L2E);
        s += e[i];
    }
#pragma unroll
    for (int off = 32; off >= 1; off >>= 1)
        s += __shfl_xor(s, off);
    if ((tid & 63) == 0) red[tid >> 6] = s;
    __syncthreads();
    s = (red[0] + red[1]) + (red[2] + red[3]);
    float inv = __builtin_amdgcn_rcpf(s);
    float4 o = make_float4(e[0] * inv, e[1] * inv, e[2] * inv, e[3] * inv);
    *(float4*)(srow + tid * 4) = o;
}

// ---------------------------------------------------------------------------
// attns[b] = W[b] (128x1024) @ M[b] (1024x512). LDS-tiled GEMM (unchanged).
// ---------------------------------------------------------------------------
__global__ __launch_bounds__(256) void attn_out_kernel(
    const float* __restrict__ wgt, const float* __restrict__ mem,
    float* __restrict__ out) {
    const int bid = blockIdx.x;
    const int b  = bid & 7;
    const int j2 = bid >> 3;
    const int mt = j2 & 3;
    const int nt = j2 >> 2;
    const int t = threadIdx.x;
    __shared__ float As[32][34];
    __shared__ float Bs[32][64];

    const int ar = t >> 3, ac = (t & 7) << 2;
    const int br = t >> 4, bc = (t & 15) << 2;
    const float* Ap = wgt + ((size_t)(b * QL_ + mt * 32 + ar)) * ML_ + ac;
    const float* Bp = mem + ((size_t)(b * ML_ + br)) * KS_ + nt * 64 + bc;

    const int tx = t & 15, ty = t >> 4;
    float acc0[4] = {0.f, 0.f, 0.f, 0.f};
    float acc1[4] = {0.f, 0.f, 0.f, 0.f};

    float4 apre = *(const float4*)(Ap);
    float4 bpre0 = *(const float4*)(Bp);
    float4 bpre1 = *(const float4*)(Bp + (size_t)16 * KS_);

    for (int k0 = 0; k0 < ML_; k0 += 32) {
        __syncthreads();
        As[ac + 0][ar] = apre.x; As[ac + 1][ar] = apre.y;
        As[ac + 2][ar] = apre.z; As[ac + 3][ar] = apre.w;
        *(float4*)(&Bs[br][bc])      = bpre0;
        *(float4*)(&Bs[br + 16][bc]) = bpre1;
        __syncthreads();
        if (k0 + 32 < ML_) {
            apre  = *(const float4*)(Ap + k0 + 32);
            bpre0 = *(const float4*)(Bp + (size_t)(k0 + 32) * KS_);
            bpre1 = *(const float4*)(Bp + (size_t)(k0 + 48) * KS_);
        }
#pragma unroll
        for (int kk = 0; kk < 32; ++kk) {
            float2 a2 = *(const float2*)(&As[kk][ty * 2]);
            float4 b4 = *(const float4*)(&Bs[kk][tx * 4]);
            acc0[0] = fmaf(a2.x, b4.x, acc0[0]);
            acc0[1] = fmaf(a2.x, b4.y, acc0[1]);
            acc0[2] = fmaf(a2.x, b4.z, acc0[2]);
            acc0[3] = fmaf(a2.x, b4.w, acc0[3]);
            acc1[0] = fmaf(a2.y, b4.x, acc1[0]);
            acc1[1] = fmaf(a2.y, b4.y, acc1[1]);
            acc1[2] = fmaf(a2.y, b4.z, acc1[2]);
            acc1[3] = fmaf(a2.y, b4.w, acc1[3]);
        }
    }
    size_t orow = ((size_t)(b * QL_ + mt * 32 + ty * 2)) * KS_ + nt * 64 + tx * 4;
    *(float4*)(out + orow)       = make_float4(acc0[0], acc0[1], acc0[2], acc0[3]);
    *(float4*)(out + orow + KS_) = make_float4(acc1[0], acc1[1], acc1[2], acc1[3]);
}

extern "C" void kernel_launch(void* const* d_in, const int* in_sizes, int n_in,
                              void* d_out, int out_size, void* d_ws, size_t ws_size,
                              hipStream_t stream) {
    const float* query  = (const float*)d_in[0];
    const float* memory = (const float*)d_in[1];
    const unsigned char* mask = (const unsigned char*)d_in[2];
    const float* Wq = (const float*)d_in[3];
    const float* bq = (const float*)d_in[4];
    const float* Wk = (const float*)d_in[5];
    const float* bk = (const float*)d_in[6];
    const float* wl = (const float*)d_in[7];
    // d_in[8] (bl) cancels under softmax shift-invariance; not read.

    float* ws = (float*)d_ws;
    float* Eq = ws + QP_OFF;
    float* Ek = ws + KP_OFF;
    unsigned char* mcan = (unsigned char*)(ws + MASK_OFF);

    float* attns = (float*)d_out;                      // [B][QL][KS]
    float* wout  = (float*)d_out + B_ * QL_ * KS_;     // [B][QL][ML] (also sr scratch)

    proj_kernel<<<dim3(145), dim3(256), 0, stream>>>(query, memory, Wq, bq, Wk, bk,
                                                     Eq, Ek, mask, mcan);
    logits_kernel<<<dim3(1024), dim3(256), 0, stream>>>(Eq, Ek, wl, wout);
    softmax_kernel<<<dim3(B_ * QL_), dim3(256), 0, stream>>>(wout, mcan);
    attn_out_kernel<<<dim3(256), dim3(256), 0, stream>>>(wout, memory, attns);
}